// Round 2
// baseline (329.929 us; speedup 1.0000x reference)
//
#include <hip/hip_runtime.h>

#define NSTEP 365
#define NGRID 4000
#define MUENS 8
#define CAPMIN 0.00125f
#define SMINV 0.0001f
#define DEPTH 6

__device__ __forceinline__ float frcp(float x) { return __builtin_amdgcn_rcpf(x); }
__device__ __forceinline__ float fexp2(float x) { return __builtin_amdgcn_exp2f(x); }
__device__ __forceinline__ float flog2(float x) { return __builtin_amdgcn_logf(x); }

__global__ __launch_bounds__(64) void sacsma_kernel(
    const float* __restrict__ x,     // [NSTEP][NGRID][3]
    const float* __restrict__ par,   // [NSTEP][NGRID][11][MUENS]
    float* __restrict__ out)         // [NSTEP][NGRID][2]
{
    const int tid = blockIdx.x * 64 + threadIdx.x;   // 32000 threads
    const int g  = tid >> 3;
    const int mu = tid & 7;
    if (g >= NGRID) return;

    // ---- static params (from t = NSTEP-1), indices 5..10 ----
    const float* ps = par + ((size_t)(NSTEP - 1) * NGRID + g) * 88 + mu;
    const float rexp  = ps[5 * 8] * 7.0f;                  // lo 0   hi 7
    const float f3    = 0.005f + ps[6 * 8] * 0.99f;        // lo .005 hi .995
    const float f4    = 0.005f + ps[7 * 8] * 0.99f;
    const float pfree = ps[8 * 8];                         // lo 0 hi 1
    const float klzp  = ps[9 * 8];
    const float klzs  = ps[10 * 8];
    const float e1 = 1.0f + rexp;

    float S1 = 0.001f, S2 = 0.001f, S3 = 0.001f, S4 = 0.001f, S5 = 0.001f;

    const size_t pstride = (size_t)NGRID * 88;   // params per timestep
    const size_t xstride = (size_t)NGRID * 3;
    const float* pg = par + (size_t)g * 88 + mu;
    const float* xg = x + (size_t)g * 3;

    // ---- depth-6 register prefetch pipeline ----
    float bp0[DEPTH], bp1[DEPTH], bp2[DEPTH], bp3[DEPTH], bp4[DEPTH];
    float bP[DEPTH], bE[DEPTH];

    #pragma unroll
    for (int j = 0; j < DEPTH; ++j) {
        const float* pj = pg + (size_t)j * pstride;
        const float* xj = xg + (size_t)j * xstride;
        bp0[j] = pj[0];  bp1[j] = pj[8];  bp2[j] = pj[16];
        bp3[j] = pj[24]; bp4[j] = pj[32];
        bP[j] = xj[0];   bE[j] = xj[2];
    }

    const float* pgn = pg + (size_t)DEPTH * pstride;
    const float* xgn = xg + (size_t)DEPTH * xstride;

    float* og = out + (size_t)g * 2;

    for (int tb = 0; tb < NSTEP; tb += DEPTH) {
        #pragma unroll
        for (int j = 0; j < DEPTH; ++j) {
            const int t = tb + j;
            if (t >= NSTEP) break;

            // consume slot j
            const float c0 = bp0[j], c1 = bp1[j], c2 = bp2[j], c3 = bp3[j], c4 = bp4[j];
            const float P = bP[j], Ep = bE[j];

            // refill slot j for t+DEPTH (issues early, lands 6 steps later)
            if (t + DEPTH < NSTEP) {
                bp0[j] = pgn[0];  bp1[j] = pgn[8];  bp2[j] = pgn[16];
                bp3[j] = pgn[24]; bp4[j] = pgn[32];
                bP[j] = xgn[0];   bE[j] = xgn[2];
                pgn += pstride; xgn += xstride;
            }

            // ---- parameter transforms (time-varying 0..4) ----
            const float pctim = c0;                        // lo 0 hi 1
            const float smax  = 1.0f + c1 * 1999.0f;       // lo 1 hi 2000
            const float f1    = 0.005f + c2 * 0.99f;
            const float f2    = 0.005f + c3 * 0.99f;
            const float kuz   = c4;                        // lo 0 hi 1

            const float uztwm = f1 * smax;
            float rem = smax - uztwm;
            const float uzfwm = fmaxf(CAPMIN, f2 * rem);
            rem = rem - uzfwm;
            const float lztwm = fmaxf(CAPMIN, f3 * rem);
            rem = rem - lztwm;
            const float lzfwpm = fmaxf(CAPMIN, f4 * rem);
            const float lzfwsm = fmaxf(CAPMIN, (1.0f - f4) * rem);
            const float pbase  = lzfwpm * klzp + lzfwsm * klzs;
            const float invden = frcp(pbase);
            const float zperc  = fminf(100000.0f,
                (lztwm + lzfwsm * (1.0f - klzs)) * invden + lzfwpm * (1.0f - klzp) * invden);

            const float inv_uztwm = frcp(uztwm);
            const float inv_uzfwm = frcp(uzfwm);
            const float inv_lztwm = frcp(lztwm);

            // ---- fluxes ----
            const float qdir = pctim * P;
            const float peff = (1.0f - pctim) * P;

            const float ru = (S1 * inv_uztwm < S2 * inv_uzfwm)
                ? (S2 * uztwm - S1 * uzfwm) * frcp(uztwm + uzfwm) : 0.0f;

            const float euztw = fminf(S1 * inv_uztwm * Ep, S1);
            const float twexu = (S1 >= uztwm) ? peff : 0.0f;
            const float qsur  = (S2 >= uzfwm) ? twexu : 0.0f;
            const float qint  = kuz * S2;
            const float euzfw = fminf(fmaxf(0.0f, Ep - euztw), S2);

            const float deficit = fmaxf(1e-8f, lztwm - S3)
                                + fmaxf(1e-8f, lzfwpm - S4)
                                + fmaxf(1e-8f, lzfwsm - S5);
            const float defmax  = fmaxf(1e-8f, lztwm + lzfwpm + lzfwsm);
            const float ratio   = deficit * frcp(defmax);
            const float powterm = fexp2(e1 * flog2(ratio));   // ratio in (0, ~1]
            float pc = pbase * (1.0f + zperc * powterm) * S2 * inv_uzfwm;
            pc = fmaxf(0.0f, fminf(pc, S2));

            const float pctw  = (1.0f - pfree) * pc;
            const float elztw = fminf(S3 * inv_lztwm * fmaxf(0.0f, Ep - euztw - euzfw), S3);
            const float twexl = (S3 >= lztwm) ? pctw : 0.0f;

            // deficit_dist for fp / fs
            const float d1  = fmaxf(0.0f, 1.0f - S4 * frcp(lzfwpm));
            const float d2  = fmaxf(0.0f, 1.0f - S5 * frcp(lzfwsm));
            const float tot = d1 + d2;
            const float invtot = frcp(tot);
            const float invpm  = frcp(lzfwpm + lzfwsm);
            const float fp = (tot > 0.0f) ? d1 * invtot : lzfwpm * invpm;
            const float fs = (tot > 0.0f) ? d2 * invtot : lzfwsm * invpm;

            const float twexlp = fp * twexl;
            const float twexls = fs * twexl;
            const float pcfwp  = pfree * fp * pc;
            const float pcfws  = pfree * fs * pc;

            const float inv3 = frcp(lztwm + lzfwpm + lzfwsm);
            const float s3r  = S3 * inv_lztwm;
            const float rlp  = (s3r < (S4 + S5) * invpm) ? (S4 * lztwm - S3 * lzfwpm) * inv3 : 0.0f;
            const float rls  = (s3r < (S5 + S4) * invpm) ? (S5 * lztwm - S3 * lzfwsm) * inv3 : 0.0f;

            const float qbfp = klzp * S4;
            const float qbfs = klzs * S5;

            // ---- state updates ----
            S1 = fmaxf(S1 + peff + ru - euztw - twexu, SMINV);
            S2 = fmaxf(S2 + twexu - euzfw - qsur - qint - ru - pc, SMINV);
            S3 = fmaxf(S3 + pctw + rlp + rls - elztw - twexl, SMINV);
            S4 = fmaxf(S4 + twexlp + pcfwp - rlp - qbfp, SMINV);
            S5 = fmaxf(S5 + twexls + pcfws - rls - qbfs, SMINV);

            float qsim = qdir + qsur + qint + qbfp + qbfs;
            float et   = euztw + euzfw + elztw;

            // ---- mu-mean over the 8-lane group ----
            qsim += __shfl_xor(qsim, 1); qsim += __shfl_xor(qsim, 2); qsim += __shfl_xor(qsim, 4);
            et   += __shfl_xor(et, 1);   et   += __shfl_xor(et, 2);   et   += __shfl_xor(et, 4);

            if (mu == 0) {
                float2 o = make_float2(qsim * 0.125f, et * 0.125f);
                *reinterpret_cast<float2*>(og + (size_t)t * NGRID * 2) = o;
            }
        }
    }
}

extern "C" void kernel_launch(void* const* d_in, const int* in_sizes, int n_in,
                              void* d_out, int out_size, void* d_ws, size_t ws_size,
                              hipStream_t stream) {
    const float* x   = (const float*)d_in[0];   // (365, 4000, 3)
    const float* par = (const float*)d_in[1];   // (365, 4000, 11, 8)
    float* out = (float*)d_out;                 // (365, 4000, 2)

    const int threads = NGRID * MUENS;          // 32000
    sacsma_kernel<<<(threads + 63) / 64, 64, 0, stream>>>(x, par, out);
}

// Round 3
// 178.946 us; speedup vs baseline: 1.8437x; 1.8437x over previous
//
#include <hip/hip_runtime.h>

#define NSTEP 365
#define NGRID 4000
#define MUENS 8
#define CAPMIN 0.00125f
#define SMINV 0.0001f
// 365 = 5 * 73, so DEPTH=5 gives a tail-free pipeline
#define DEPTH 5

__device__ __forceinline__ float frcp(float x) { return __builtin_amdgcn_rcpf(x); }
__device__ __forceinline__ float fexp2(float x) { return __builtin_amdgcn_exp2f(x); }
__device__ __forceinline__ float flog2(float x) { return __builtin_amdgcn_logf(x); }

__device__ __forceinline__ void sac_step(
    float c0, float c1, float c2, float c3, float c4,
    float P, float Ep,
    float e1, float f3, float f4, float pfree, float klzp, float klzs,
    float& S1, float& S2, float& S3, float& S4, float& S5,
    float* __restrict__ og, int t, int mu)
{
    // ---- parameter transforms (time-varying 0..4) ----
    const float pctim = c0;                        // lo 0 hi 1
    const float smax  = 1.0f + c1 * 1999.0f;       // lo 1 hi 2000
    const float f1    = 0.005f + c2 * 0.99f;
    const float f2    = 0.005f + c3 * 0.99f;
    const float kuz   = c4;                        // lo 0 hi 1

    const float uztwm = f1 * smax;
    float rem = smax - uztwm;
    const float uzfwm = fmaxf(CAPMIN, f2 * rem);
    rem = rem - uzfwm;
    const float lztwm = fmaxf(CAPMIN, f3 * rem);
    rem = rem - lztwm;
    const float lzfwpm = fmaxf(CAPMIN, f4 * rem);
    const float lzfwsm = fmaxf(CAPMIN, (1.0f - f4) * rem);
    const float pbase  = lzfwpm * klzp + lzfwsm * klzs;
    const float invden = frcp(pbase);
    const float zperc  = fminf(100000.0f,
        (lztwm + lzfwsm * (1.0f - klzs)) * invden + lzfwpm * (1.0f - klzp) * invden);

    const float inv_uztwm = frcp(uztwm);
    const float inv_uzfwm = frcp(uzfwm);
    const float inv_lztwm = frcp(lztwm);

    // ---- fluxes ----
    const float qdir = pctim * P;
    const float peff = (1.0f - pctim) * P;

    const float ru = (S1 * inv_uztwm < S2 * inv_uzfwm)
        ? (S2 * uztwm - S1 * uzfwm) * frcp(uztwm + uzfwm) : 0.0f;

    const float euztw = fminf(S1 * inv_uztwm * Ep, S1);
    const float twexu = (S1 >= uztwm) ? peff : 0.0f;
    const float qsur  = (S2 >= uzfwm) ? twexu : 0.0f;
    const float qint  = kuz * S2;
    const float euzfw = fminf(fmaxf(0.0f, Ep - euztw), S2);

    const float deficit = fmaxf(1e-8f, lztwm - S3)
                        + fmaxf(1e-8f, lzfwpm - S4)
                        + fmaxf(1e-8f, lzfwsm - S5);
    const float defmax  = fmaxf(1e-8f, lztwm + lzfwpm + lzfwsm);
    const float ratio   = deficit * frcp(defmax);
    const float powterm = fexp2(e1 * flog2(ratio));   // ratio in (0, ~1]
    float pc = pbase * (1.0f + zperc * powterm) * S2 * inv_uzfwm;
    pc = fmaxf(0.0f, fminf(pc, S2));

    const float pctw  = (1.0f - pfree) * pc;
    const float elztw = fminf(S3 * inv_lztwm * fmaxf(0.0f, Ep - euztw - euzfw), S3);
    const float twexl = (S3 >= lztwm) ? pctw : 0.0f;

    // deficit_dist for fp / fs
    const float d1  = fmaxf(0.0f, 1.0f - S4 * frcp(lzfwpm));
    const float d2  = fmaxf(0.0f, 1.0f - S5 * frcp(lzfwsm));
    const float tot = d1 + d2;
    const float invtot = frcp(tot);
    const float invpm  = frcp(lzfwpm + lzfwsm);
    const float fp = (tot > 0.0f) ? d1 * invtot : lzfwpm * invpm;
    const float fs = (tot > 0.0f) ? d2 * invtot : lzfwsm * invpm;

    const float twexlp = fp * twexl;
    const float twexls = fs * twexl;
    const float pcfwp  = pfree * fp * pc;
    const float pcfws  = pfree * fs * pc;

    const float inv3 = frcp(lztwm + lzfwpm + lzfwsm);
    const float s3r  = S3 * inv_lztwm;
    const float rlp  = (s3r < (S4 + S5) * invpm) ? (S4 * lztwm - S3 * lzfwpm) * inv3 : 0.0f;
    const float rls  = (s3r < (S5 + S4) * invpm) ? (S5 * lztwm - S3 * lzfwsm) * inv3 : 0.0f;

    const float qbfp = klzp * S4;
    const float qbfs = klzs * S5;

    // ---- state updates ----
    S1 = fmaxf(S1 + peff + ru - euztw - twexu, SMINV);
    S2 = fmaxf(S2 + twexu - euzfw - qsur - qint - ru - pc, SMINV);
    S3 = fmaxf(S3 + pctw + rlp + rls - elztw - twexl, SMINV);
    S4 = fmaxf(S4 + twexlp + pcfwp - rlp - qbfp, SMINV);
    S5 = fmaxf(S5 + twexls + pcfws - rls - qbfs, SMINV);

    float qsim = qdir + qsur + qint + qbfp + qbfs;
    float et   = euztw + euzfw + elztw;

    // ---- mu-mean over the 8-lane group ----
    qsim += __shfl_xor(qsim, 1); qsim += __shfl_xor(qsim, 2); qsim += __shfl_xor(qsim, 4);
    et   += __shfl_xor(et, 1);   et   += __shfl_xor(et, 2);   et   += __shfl_xor(et, 4);

    if (mu == 0) {
        float2 o = make_float2(qsim * 0.125f, et * 0.125f);
        *reinterpret_cast<float2*>(og + (size_t)t * NGRID * 2) = o;
    }
}

// Named-register pipeline slots — NO arrays, NO runtime indexing (avoids scratch).
#define DECL_SLOT(j) float p0_##j, p1_##j, p2_##j, p3_##j, p4_##j, Px_##j, Ex_##j;

#define LOAD_SLOT(j, pbase, xbase) do {                                   \
    const float* pj_ = (pbase) + (size_t)(j) * pstride;                   \
    const float* xj_ = (xbase) + (size_t)(j) * xstride;                   \
    p0_##j = pj_[0];  p1_##j = pj_[8];  p2_##j = pj_[16];                 \
    p3_##j = pj_[24]; p4_##j = pj_[32];                                   \
    Px_##j = xj_[0];  Ex_##j = xj_[2];                                    \
} while (0)

#define DO_STEP(j) do {                                                   \
    const float c0_ = p0_##j, c1_ = p1_##j, c2_ = p2_##j,                 \
                c3_ = p3_##j, c4_ = p4_##j;                               \
    const float P_ = Px_##j, E_ = Ex_##j;                                 \
    LOAD_SLOT(j, pb, xb);   /* refill for t+DEPTH, lands 5 steps later */ \
    sac_step(c0_, c1_, c2_, c3_, c4_, P_, E_,                             \
             e1, f3, f4, pfree, klzp, klzs,                               \
             S1, S2, S3, S4, S5, og, tbase + (j), mu);                    \
} while (0)

__global__ __launch_bounds__(64) void sacsma_kernel(
    const float* __restrict__ x,     // [NSTEP][NGRID][3]
    const float* __restrict__ par,   // [NSTEP][NGRID][11][MUENS]
    float* __restrict__ out)         // [NSTEP][NGRID][2]
{
    const int tid = blockIdx.x * 64 + threadIdx.x;   // 32000 threads
    const int g  = tid >> 3;
    const int mu = tid & 7;
    if (g >= NGRID) return;

    // ---- static params (from t = NSTEP-1), indices 5..10 ----
    const float* ps = par + ((size_t)(NSTEP - 1) * NGRID + g) * 88 + mu;
    const float rexp  = ps[5 * 8] * 7.0f;                  // lo 0   hi 7
    const float f3    = 0.005f + ps[6 * 8] * 0.99f;        // lo .005 hi .995
    const float f4    = 0.005f + ps[7 * 8] * 0.99f;
    const float pfree = ps[8 * 8];                         // lo 0 hi 1
    const float klzp  = ps[9 * 8];
    const float klzs  = ps[10 * 8];
    const float e1 = 1.0f + rexp;

    float S1 = 0.001f, S2 = 0.001f, S3 = 0.001f, S4 = 0.001f, S5 = 0.001f;

    const size_t pstride = (size_t)NGRID * 88;   // params per timestep
    const size_t xstride = (size_t)NGRID * 3;
    const float* pg = par + (size_t)g * 88 + mu;
    const float* xg = x + (size_t)g * 3;
    float* og = out + (size_t)g * 2;

    DECL_SLOT(0) DECL_SLOT(1) DECL_SLOT(2) DECL_SLOT(3) DECL_SLOT(4)

    // prime the pipeline: t = 0..4
    {
        const float* pb = pg;
        const float* xb = xg;
        LOAD_SLOT(0, pb, xb); LOAD_SLOT(1, pb, xb); LOAD_SLOT(2, pb, xb);
        LOAD_SLOT(3, pb, xb); LOAD_SLOT(4, pb, xb);
    }

    for (int ob = 0; ob < NSTEP / DEPTH; ++ob) {       // 73 blocks, no tail
        const int tbase = ob * DEPTH;
        // prefetch base for t+DEPTH; last block clamps to t=0 (garbage loads,
        // never consumed — keeps addresses in-bounds with no per-step branch)
        const int pt = (ob < NSTEP / DEPTH - 1) ? (tbase + DEPTH) : 0;
        const float* pb = pg + (size_t)pt * pstride;
        const float* xb = xg + (size_t)pt * xstride;

        DO_STEP(0); DO_STEP(1); DO_STEP(2); DO_STEP(3); DO_STEP(4);
    }
}

extern "C" void kernel_launch(void* const* d_in, const int* in_sizes, int n_in,
                              void* d_out, int out_size, void* d_ws, size_t ws_size,
                              hipStream_t stream) {
    const float* x   = (const float*)d_in[0];   // (365, 4000, 3)
    const float* par = (const float*)d_in[1];   // (365, 4000, 11, 8)
    float* out = (float*)d_out;                 // (365, 4000, 2)

    const int threads = NGRID * MUENS;          // 32000
    sacsma_kernel<<<(threads + 63) / 64, 64, 0, stream>>>(x, par, out);
}